// Round 3
// baseline (6316.124 us; speedup 1.0000x reference)
//
#include <hip/hip_runtime.h>
#include <math.h>

#define NN 50000
#define NE 600000
#define D  128

// async global->LDS, 16B per lane. LDS dest must be linear in lane order.
__device__ __forceinline__ void gl_lds16(const float* g, float* l) {
    __builtin_amdgcn_global_load_lds(
        (const __attribute__((address_space(1))) void*)g,
        (__attribute__((address_space(3))) void*)l,
        16, 0, 0);
}

// ---------------------------------------------------------------------------
// Kernel A: proj = X @ W + b -> h (d_out), Q, K, V (ws)
// Tile 32 rows x 64 cols, K chunked 4x32 (W double-buffered).
// LDS 32 KB -> 5 blocks/CU (20 waves). X_s XOR-swizzled via pre-swizzled src.
// ---------------------------------------------------------------------------
__global__ __launch_bounds__(256, 5) void node_proj_kernel(
    const float* __restrict__ X,      // [NN][128]
    const float* __restrict__ W,      // [128][512]
    const float* __restrict__ bias,   // [512]
    float* __restrict__ out_h,
    float* __restrict__ Qp, float* __restrict__ Kp, float* __restrict__ Vp)
{
    __shared__ float X_s[32 * 128];        // 16 KB, swizzled 16B-groups
    __shared__ float W_s[2][32 * 64];      // 2 x 8 KB

    const int tid = threadIdx.x;
    const int bm  = blockIdx.x >> 3;
    const int bn  = blockIdx.x & 7;
    const int m0  = bm * 32;
    const int n0  = bn * 64;

    // stage X tile: LDS linear, source pre-swizzled (group g <- g ^ row)
#pragma unroll
    for (int it = 0; it < 4; ++it) {
        int j   = tid + it * 256;          // 1024 float4
        int row = j >> 5;
        int g   = j & 31;
        int gr  = m0 + row; if (gr > NN - 1) gr = NN - 1;   // clamp tail
        gl_lds16(X + (size_t)gr * D + ((g ^ row) << 2), &X_s[j * 4]);
    }
    // stage W chunk 0: rows 0..31, cols n0..n0+63
#pragma unroll
    for (int it = 0; it < 2; ++it) {
        int j  = tid + it * 256;           // 512 float4
        int r  = j >> 4;
        int c4 = j & 15;
        gl_lds16(W + (size_t)r * 512 + n0 + (c4 << 2), &W_s[0][j * 4]);
    }
    __syncthreads();

    const int tx = tid & 15;               // 4 cols
    const int ty = tid >> 4;               // 2 rows
    float acc[2][4] = {};

    for (int kc = 0; kc < 4; ++kc) {
        const int buf = kc & 1;
        if (kc < 3) {
            const float* Wc = W + (size_t)(kc + 1) * 32 * 512 + n0;
#pragma unroll
            for (int it = 0; it < 2; ++it) {
                int j  = tid + it * 256;
                int r  = j >> 4;
                int c4 = j & 15;
                gl_lds16(Wc + (size_t)r * 512 + (c4 << 2), &W_s[buf ^ 1][j * 4]);
            }
        }
#pragma unroll
        for (int k0 = 0; k0 < 32; k0 += 4) {
            const int k4 = (kc * 32 + k0) >> 2;
            float a[2][4], b[4][4];
#pragma unroll
            for (int i = 0; i < 2; ++i) {
                int row = ty * 2 + i;
                *(float4*)a[i] = *(const float4*)&X_s[row * 128 + ((k4 ^ row) << 2)];
            }
#pragma unroll
            for (int j = 0; j < 4; ++j)
                *(float4*)b[j] = *(const float4*)&W_s[buf][(k0 + j) * 64 + (tx << 2)];
#pragma unroll
            for (int i = 0; i < 2; ++i)
#pragma unroll
                for (int j = 0; j < 4; ++j)
#pragma unroll
                    for (int c = 0; c < 4; ++c)
                        acc[i][c] += a[i][j] * b[j][c];
        }
        __syncthreads();
    }

    const int sec = bn >> 1;               // 0:h 1:Q 2:K 3:V
    const int d0  = (bn & 1) * 64 + (tx << 2);
    float* dst = (sec == 0) ? out_h : (sec == 1) ? Qp : (sec == 2) ? Kp : Vp;
    float4 bi = *(const float4*)&bias[n0 + (tx << 2)];
#pragma unroll
    for (int i = 0; i < 2; ++i) {
        int m = m0 + ty * 2 + i;
        if (m < NN) {
            float4 r;
            r.x = acc[i][0] + bi.x;
            r.y = acc[i][1] + bi.y;
            r.z = acc[i][2] + bi.z;
            r.w = acc[i][3] + bi.w;
            *(float4*)&dst[(size_t)m * D + d0] = r;
        }
    }
}

// ---------------------------------------------------------------------------
// Kernel B: ep = ef @ We + web ; eta = sigmoid(Q[r]+K[s]+ep)
//           atomicAdd(out[r], eta * V[s])
// Tile 32 edges x 128 dims (EF staged ONCE). We in 4 K-chunks, dbuf.
// LDS 48 KB -> 3 blocks/CU. Gathers prefetched before the K-loop.
// ---------------------------------------------------------------------------
__global__ __launch_bounds__(256, 3) void edge_kernel(
    const float* __restrict__ EF,     // [NE][128]
    const int*   __restrict__ snd,
    const int*   __restrict__ rcv,
    const float* __restrict__ We,     // [128][128]
    const float* __restrict__ web,    // [128]
    const float* __restrict__ Qp, const float* __restrict__ Kp,
    const float* __restrict__ Vp,
    float* __restrict__ out)
{
    __shared__ float ef_s[32 * 128];       // 16 KB, linear (2-way reads = free)
    __shared__ float We_s[2][32 * 128];    // 2 x 16 KB

    const int tid = threadIdx.x;
    const int e0  = blockIdx.x * 32;
    const int tx  = tid & 31;              // dim float4 lane: d0 = tx*4
    const int ty  = tid >> 5;              // 8 groups x 4 edges

    // stage ef tile: 16 KB fully linear
#pragma unroll
    for (int it = 0; it < 4; ++it) {
        int j = tid + it * 256;
        gl_lds16(EF + (size_t)e0 * D + j * 4, &ef_s[j * 4]);
    }
    // stage We chunk 0 (rows 0..31, full width): 16 KB linear
#pragma unroll
    for (int it = 0; it < 4; ++it) {
        int j = tid + it * 256;
        gl_lds16(We + j * 4, &We_s[0][j * 4]);
    }

    // prefetch epilogue operands (latency hides under K-loop)
    const int d0 = tx << 2;
    int sidx[4], ridx[4];
#pragma unroll
    for (int i = 0; i < 4; ++i) {
        int e = e0 + ty * 4 + i;
        sidx[i] = snd[e];
        ridx[i] = rcv[e];
    }
    float4 q[4], kk[4], v[4];
#pragma unroll
    for (int i = 0; i < 4; ++i) {
        q[i]  = *(const float4*)&Qp[(size_t)ridx[i] * D + d0];
        kk[i] = *(const float4*)&Kp[(size_t)sidx[i] * D + d0];
        v[i]  = *(const float4*)&Vp[(size_t)sidx[i] * D + d0];
    }
    __syncthreads();

    float acc[4][4] = {};
    for (int kc = 0; kc < 4; ++kc) {
        const int buf = kc & 1;
        if (kc < 3) {
            const float* Wc = We + (size_t)(kc + 1) * 32 * D;
#pragma unroll
            for (int it = 0; it < 4; ++it) {
                int j = tid + it * 256;
                gl_lds16(Wc + j * 4, &We_s[buf ^ 1][j * 4]);
            }
        }
#pragma unroll
        for (int k0 = 0; k0 < 32; k0 += 4) {
            float a[4][4], b[4][4];
#pragma unroll
            for (int i = 0; i < 4; ++i)
                *(float4*)a[i] = *(const float4*)&ef_s[(ty * 4 + i) * 128 + kc * 32 + k0];
#pragma unroll
            for (int j = 0; j < 4; ++j)
                *(float4*)b[j] = *(const float4*)&We_s[buf][(k0 + j) * 128 + d0];
#pragma unroll
            for (int i = 0; i < 4; ++i)
#pragma unroll
                for (int j = 0; j < 4; ++j)
#pragma unroll
                    for (int c = 0; c < 4; ++c)
                        acc[i][c] += a[i][j] * b[j][c];
        }
        __syncthreads();
    }

    float4 wb = *(const float4*)&web[d0];
#pragma unroll
    for (int i = 0; i < 4; ++i) {
        float x0 = q[i].x + kk[i].x + acc[i][0] + wb.x;
        float x1 = q[i].y + kk[i].y + acc[i][1] + wb.y;
        float x2 = q[i].z + kk[i].z + acc[i][2] + wb.z;
        float x3 = q[i].w + kk[i].w + acc[i][3] + wb.w;
        float g0 = 1.f / (1.f + __expf(-x0));
        float g1 = 1.f / (1.f + __expf(-x1));
        float g2 = 1.f / (1.f + __expf(-x2));
        float g3 = 1.f / (1.f + __expf(-x3));
        float* op = out + (size_t)ridx[i] * D + d0;
        atomicAdd(op + 0, g0 * v[i].x);
        atomicAdd(op + 1, g1 * v[i].y);
        atomicAdd(op + 2, g2 * v[i].z);
        atomicAdd(op + 3, g3 * v[i].w);
    }
}

extern "C" void kernel_launch(void* const* d_in, const int* in_sizes, int n_in,
                              void* d_out, int out_size, void* d_ws, size_t ws_size,
                              hipStream_t stream)
{
    const float* X   = (const float*)d_in[0];
    const int*   snd = (const int*)  d_in[1];
    const int*   rcv = (const int*)  d_in[2];
    const float* EF  = (const float*)d_in[3];
    const float* W   = (const float*)d_in[4];
    const float* Wb  = (const float*)d_in[5];
    const float* We  = (const float*)d_in[6];
    const float* Web = (const float*)d_in[7];
    float* out = (float*)d_out;

    float* Qp = (float*)d_ws;                       // [NN][128]
    float* Kp = Qp + (size_t)NN * D;
    float* Vp = Kp + (size_t)NN * D;

    const int gridA = ((NN + 31) / 32) * 8;         // 1563 * 8 = 12504
    node_proj_kernel<<<gridA, 256, 0, stream>>>(X, W, Wb, out, Qp, Kp, Vp);

    const int gridB = NE / 32;                      // 18750
    edge_kernel<<<gridB, 256, 0, stream>>>(EF, snd, rcv, We, Web, Qp, Kp, Vp, out);
}

// Round 4
// 1994.810 us; speedup vs baseline: 3.1663x; 3.1663x over previous
//
#include <hip/hip_runtime.h>
#include <math.h>

#define NN 50000
#define NE 600000
#define D  128

// ---------------------------------------------------------------------------
// Kernel A: proj = X @ W + b -> h (d_out), Q, K, V (ws)
// Tile 64 rows x 64 cols. A_s 32 KB (XOR-swizzled), W dbuf 2x8 KB = 48 KB LDS
// -> 3 blocks/CU. W register-staged double buffer, one barrier per K-chunk.
// ---------------------------------------------------------------------------
__global__ __launch_bounds__(256) void node_proj_kernel(
    const float* __restrict__ X,      // [NN][128]
    const float* __restrict__ W,      // [128][512]
    const float* __restrict__ bias,   // [512]
    float* __restrict__ out_h,
    float* __restrict__ Qp, float* __restrict__ Kp, float* __restrict__ Vp)
{
    __shared__ float A_s[64 * 128];        // 32 KB, 16B-group XOR swizzle
    __shared__ float W_s[2][32 * 64];      // 2 x 8 KB

    const int tid = threadIdx.x;
    const int bm  = blockIdx.x >> 3;
    const int bn  = blockIdx.x & 7;
    const int m0  = bm * 64;
    const int n0  = bn * 64;

    // stage A (64x128): plain loads + swizzled ds_write
#pragma unroll
    for (int it = 0; it < 8; ++it) {
        int j   = tid + it * 256;          // 2048 float4
        int row = j >> 5;
        int c4  = j & 31;
        float4 v = make_float4(0.f, 0.f, 0.f, 0.f);
        int gr = m0 + row;
        if (gr < NN) v = *(const float4*)&X[(size_t)gr * D + (c4 << 2)];
        *(float4*)&A_s[row * 128 + ((c4 ^ (row & 31)) << 2)] = v;
    }
    // stage W chunk 0 (k-rows 0..31, cols n0..n0+63)
#pragma unroll
    for (int it = 0; it < 2; ++it) {
        int j  = tid + it * 256;           // 512 float4
        int r  = j >> 4;
        int c4 = j & 15;
        *(float4*)&W_s[0][j * 4] = *(const float4*)&W[(size_t)r * 512 + n0 + (c4 << 2)];
    }
    __syncthreads();

    const int tx = tid & 15;               // 4 cols
    const int ty = tid >> 4;               // 4 rows
    float acc[4][4] = {};
    float4 wreg[2];

    for (int kc = 0; kc < 4; ++kc) {
        const int buf = kc & 1;
        if (kc < 3) {                      // issue next-chunk loads early
#pragma unroll
            for (int it = 0; it < 2; ++it) {
                int j  = tid + it * 256;
                int r  = j >> 4;
                int c4 = j & 15;
                wreg[it] = *(const float4*)&W[(size_t)((kc + 1) * 32 + r) * 512 + n0 + (c4 << 2)];
            }
        }
#pragma unroll
        for (int k0 = 0; k0 < 32; k0 += 4) {
            const int k4 = (kc * 32 + k0) >> 2;
            float a[4][4], b[4][4];
#pragma unroll
            for (int i = 0; i < 4; ++i) {
                int row = ty * 4 + i;
                *(float4*)a[i] = *(const float4*)&A_s[row * 128 + ((k4 ^ (row & 31)) << 2)];
            }
#pragma unroll
            for (int j = 0; j < 4; ++j)
                *(float4*)b[j] = *(const float4*)&W_s[buf][(k0 + j) * 64 + (tx << 2)];
#pragma unroll
            for (int i = 0; i < 4; ++i)
#pragma unroll
                for (int j = 0; j < 4; ++j)
#pragma unroll
                    for (int c = 0; c < 4; ++c)
                        acc[i][c] += a[i][j] * b[j][c];
        }
        if (kc < 3) {                      // write-late into the other buffer
#pragma unroll
            for (int it = 0; it < 2; ++it) {
                int j = tid + it * 256;
                *(float4*)&W_s[buf ^ 1][j * 4] = wreg[it];
            }
        }
        __syncthreads();
    }

    const int sec = bn >> 1;               // 0:h 1:Q 2:K 3:V
    const int d0  = (bn & 1) * 64 + (tx << 2);
    float* dst = (sec == 0) ? out_h : (sec == 1) ? Qp : (sec == 2) ? Kp : Vp;
    float4 bi = *(const float4*)&bias[n0 + (tx << 2)];
#pragma unroll
    for (int i = 0; i < 4; ++i) {
        int m = m0 + ty * 4 + i;
        if (m < NN) {
            float4 r;
            r.x = acc[i][0] + bi.x;
            r.y = acc[i][1] + bi.y;
            r.z = acc[i][2] + bi.z;
            r.w = acc[i][3] + bi.w;
            *(float4*)&dst[(size_t)m * D + d0] = r;
        }
    }
}

// ---------------------------------------------------------------------------
// Kernel B: ep = ef @ We + web ; eta = sigmoid(Q[r]+K[s]+ep)
//           atomicAdd(out[r], eta * V[s])
// Tile 32 edges x 128 dims (EF staged ONCE, fully linear).
// ef_s 16 KB + We dbuf 2x16 KB = 48 KB -> 3 blocks/CU.
// We register-staged dbuf; gathers prefetched before the K-loop.
// ---------------------------------------------------------------------------
__global__ __launch_bounds__(256) void edge_kernel(
    const float* __restrict__ EF,     // [NE][128]
    const int*   __restrict__ snd,
    const int*   __restrict__ rcv,
    const float* __restrict__ We,     // [128][128]
    const float* __restrict__ web,    // [128]
    const float* __restrict__ Qp, const float* __restrict__ Kp,
    const float* __restrict__ Vp,
    float* __restrict__ out)
{
    __shared__ float ef_s[32 * 128];       // 16 KB linear (reads are 2-way = free)
    __shared__ float We_s[2][32 * 128];    // 2 x 16 KB

    const int tid = threadIdx.x;
    const int e0  = blockIdx.x * 32;
    const int tx  = tid & 31;              // d0 = tx*4 (128 dims)
    const int ty  = tid >> 5;              // 8 groups x 4 edges

    // stage ef tile: fully linear, coalesced
#pragma unroll
    for (int it = 0; it < 4; ++it) {
        int j = tid + it * 256;            // 1024 float4
        *(float4*)&ef_s[j * 4] = *(const float4*)&EF[(size_t)e0 * D + j * 4];
    }
    // stage We chunk 0 (k-rows 0..31, all 128 cols): linear
#pragma unroll
    for (int it = 0; it < 4; ++it) {
        int j = tid + it * 256;
        *(float4*)&We_s[0][j * 4] = *(const float4*)&We[j * 4];
    }

    // prefetch epilogue operands (latency hides under the K-loop)
    const int d0 = tx << 2;
    int sidx[4], ridx[4];
#pragma unroll
    for (int i = 0; i < 4; ++i) {
        int e = e0 + ty * 4 + i;
        sidx[i] = snd[e];
        ridx[i] = rcv[e];
    }
    float4 q[4], kk[4], v[4];
#pragma unroll
    for (int i = 0; i < 4; ++i) {
        q[i]  = *(const float4*)&Qp[(size_t)ridx[i] * D + d0];
        kk[i] = *(const float4*)&Kp[(size_t)sidx[i] * D + d0];
        v[i]  = *(const float4*)&Vp[(size_t)sidx[i] * D + d0];
    }
    __syncthreads();

    float acc[4][4] = {};
    float4 wreg[4];

    for (int kc = 0; kc < 4; ++kc) {
        const int buf = kc & 1;
        if (kc < 3) {                      // issue next We chunk early
#pragma unroll
            for (int it = 0; it < 4; ++it) {
                int j = tid + it * 256;
                wreg[it] = *(const float4*)&We[(size_t)(kc + 1) * 32 * D + j * 4];
            }
        }
#pragma unroll
        for (int k0 = 0; k0 < 32; k0 += 4) {
            float a[4][4], b[4][4];
#pragma unroll
            for (int i = 0; i < 4; ++i)
                *(float4*)a[i] = *(const float4*)&ef_s[(ty * 4 + i) * 128 + kc * 32 + k0];
#pragma unroll
            for (int j = 0; j < 4; ++j)
                *(float4*)b[j] = *(const float4*)&We_s[buf][(k0 + j) * 128 + d0];
#pragma unroll
            for (int i = 0; i < 4; ++i)
#pragma unroll
                for (int j = 0; j < 4; ++j)
#pragma unroll
                    for (int c = 0; c < 4; ++c)
                        acc[i][c] += a[i][j] * b[j][c];
        }
        if (kc < 3) {                      // write-late into the other buffer
#pragma unroll
            for (int it = 0; it < 4; ++it) {
                int j = tid + it * 256;
                *(float4*)&We_s[buf ^ 1][j * 4] = wreg[it];
            }
        }
        __syncthreads();
    }

    float4 wb = *(const float4*)&web[d0];
#pragma unroll
    for (int i = 0; i < 4; ++i) {
        float x0 = q[i].x + kk[i].x + acc[i][0] + wb.x;
        float x1 = q[i].y + kk[i].y + acc[i][1] + wb.y;
        float x2 = q[i].z + kk[i].z + acc[i][2] + wb.z;
        float x3 = q[i].w + kk[i].w + acc[i][3] + wb.w;
        float g0 = 1.f / (1.f + __expf(-x0));
        float g1 = 1.f / (1.f + __expf(-x1));
        float g2 = 1.f / (1.f + __expf(-x2));
        float g3 = 1.f / (1.f + __expf(-x3));
        float* op = out + (size_t)ridx[i] * D + d0;
        atomicAdd(op + 0, g0 * v[i].x);
        atomicAdd(op + 1, g1 * v[i].y);
        atomicAdd(op + 2, g2 * v[i].z);
        atomicAdd(op + 3, g3 * v[i].w);
    }
}

extern "C" void kernel_launch(void* const* d_in, const int* in_sizes, int n_in,
                              void* d_out, int out_size, void* d_ws, size_t ws_size,
                              hipStream_t stream)
{
    const float* X   = (const float*)d_in[0];
    const int*   snd = (const int*)  d_in[1];
    const int*   rcv = (const int*)  d_in[2];
    const float* EF  = (const float*)d_in[3];
    const float* W   = (const float*)d_in[4];
    const float* Wb  = (const float*)d_in[5];
    const float* We  = (const float*)d_in[6];
    const float* Web = (const float*)d_in[7];
    float* out = (float*)d_out;

    float* Qp = (float*)d_ws;                       // [NN][128]
    float* Kp = Qp + (size_t)NN * D;
    float* Vp = Kp + (size_t)NN * D;

    const int gridA = ((NN + 63) / 64) * 8;         // 782 * 8 = 6256
    node_proj_kernel<<<gridA, 256, 0, stream>>>(X, W, Wb, out, Qp, Kp, Vp);

    const int gridB = NE / 32;                      // 18750
    edge_kernel<<<gridB, 256, 0, stream>>>(EF, snd, rcv, We, Web, Qp, Kp, Vp, out);
}

// Round 5
// 848.647 us; speedup vs baseline: 7.4426x; 2.3506x over previous
//
#include <hip/hip_runtime.h>
#include <math.h>

#define NN 50000
#define NE 600000
#define D  128

typedef __attribute__((ext_vector_type(8))) short bf16x8;
typedef __attribute__((ext_vector_type(4))) float f32x4;

__device__ __forceinline__ short f2bf(float f) {
    union { float f; unsigned u; } c; c.f = f;
    unsigned r = c.u + 0x7fff + ((c.u >> 16) & 1);   // RNE
    return (short)(r >> 16);
}

__device__ __forceinline__ bf16x8 pack8(const float* p) {
    float4 lo = *(const float4*)p;
    float4 hi = *(const float4*)(p + 4);
    bf16x8 r;
    r[0] = f2bf(lo.x); r[1] = f2bf(lo.y); r[2] = f2bf(lo.z); r[3] = f2bf(lo.w);
    r[4] = f2bf(hi.x); r[5] = f2bf(hi.y); r[6] = f2bf(hi.z); r[7] = f2bf(hi.w);
    return r;
}

// ---------------------------------------------------------------------------
// Pre-kernel: WT[n][k] = bf16(W[k][n])  (512x128),  WeT[n][k] = bf16(We[k][n])
// Small, L2-resident, one-time per launch.
// ---------------------------------------------------------------------------
__global__ __launch_bounds__(256) void transpose_cast_kernel(
    const float* __restrict__ W, const float* __restrict__ We,
    short* __restrict__ WT, short* __restrict__ WeT)
{
    int idx = blockIdx.x * 256 + threadIdx.x;
    if (idx < 512 * 128) {
        int n = idx >> 7, k = idx & 127;
        WT[idx] = f2bf(W[k * 512 + n]);
    }
    if (idx < 128 * 128) {
        int n = idx >> 7, k = idx & 127;
        WeT[idx] = f2bf(We[k * 128 + n]);
    }
}

// ---------------------------------------------------------------------------
// Node proj (MFMA, no LDS, no barriers): block = 4 waves; wave w computes
// rows [m0, m0+16) x cols [w*128, w*128+128) of X@W+b -> h/Q/K/V.
// A-frag: lane reads X[m0 + (l&15)][ks*32 + (l>>4)*8 ..+8] f32 -> bf16.
// B-frag: straight 16B bf16 load from WT (L2-hot).
// C/D: col = l&15, row = (l>>4)*4 + reg.
// ---------------------------------------------------------------------------
__global__ __launch_bounds__(256, 4) void node_proj_kernel(
    const float* __restrict__ X,
    const short* __restrict__ WT,     // [512][128] bf16
    const float* __restrict__ bias,
    float* __restrict__ out_h,
    float* __restrict__ Qp, float* __restrict__ Kp, float* __restrict__ Vp)
{
    const int tid = threadIdx.x;
    const int w   = tid >> 6;
    const int l   = tid & 63;
    const int lr  = l & 15;
    const int lk  = l >> 4;
    const int m0  = blockIdx.x * 16;        // grid 3125, exact
    const int n0  = w * 128;

    bf16x8 af[4];
    const float* arow = X + (size_t)(m0 + lr) * D + lk * 8;
#pragma unroll
    for (int ks = 0; ks < 4; ++ks) af[ks] = pack8(arow + ks * 32);

    f32x4 acc[8];
#pragma unroll
    for (int nf = 0; nf < 8; ++nf) acc[nf] = (f32x4){0.f, 0.f, 0.f, 0.f};

    const short* bbase = WT + (size_t)(n0 + lr) * D + lk * 8;
#pragma unroll
    for (int nf = 0; nf < 8; ++nf) {
#pragma unroll
        for (int ks = 0; ks < 4; ++ks) {
            bf16x8 bf = *(const bf16x8*)(bbase + nf * 16 * D + ks * 32);
            acc[nf] = __builtin_amdgcn_mfma_f32_16x16x32_bf16(af[ks], bf, acc[nf], 0, 0, 0);
        }
    }

    float* dst = (w == 0) ? out_h : (w == 1) ? Qp : (w == 2) ? Kp : Vp;
#pragma unroll
    for (int nf = 0; nf < 8; ++nf) {
        int c = nf * 16 + lr;
        float bi = bias[n0 + c];
#pragma unroll
        for (int r = 0; r < 4; ++r) {
            int m = m0 + lk * 4 + r;
            dst[(size_t)m * D + c] = acc[nf][r] + bi;
        }
    }
}

// ---------------------------------------------------------------------------
// Edge kernel (MFMA, no LDS, no barriers): block = 4 waves; wave handles 16
// edges x all 128 dims.  ep = ef@We; eta = sigmoid(Q[r]+K[s]+ep+web);
// atomicAdd(out[r], eta*V[s]).  Gate + gathers scalar per lane in C/D layout.
// ---------------------------------------------------------------------------
__global__ __launch_bounds__(256, 4) void edge_kernel(
    const float* __restrict__ EF,
    const int*   __restrict__ snd,
    const int*   __restrict__ rcv,
    const short* __restrict__ WeT,    // [128][128] bf16
    const float* __restrict__ web,
    const float* __restrict__ Qp, const float* __restrict__ Kp,
    const float* __restrict__ Vp,
    float* __restrict__ out)
{
    const int tid = threadIdx.x;
    const int w   = tid >> 6;
    const int l   = tid & 63;
    const int lr  = l & 15;
    const int lk  = l >> 4;
    const int e0  = blockIdx.x * 64 + w * 16;   // grid 9375, exact

    // A-frags: 16 edges x K=128, f32 -> bf16 in-register
    bf16x8 af[4];
    const float* arow = EF + (size_t)(e0 + lr) * D + lk * 8;
#pragma unroll
    for (int ks = 0; ks < 4; ++ks) af[ks] = pack8(arow + ks * 32);

    // this lane's 4 edges (C/D rows): e0 + lk*4 + r
    int sidx[4], ridx[4];
#pragma unroll
    for (int r = 0; r < 4; ++r) {
        sidx[r] = snd[e0 + lk * 4 + r];
        ridx[r] = rcv[e0 + lk * 4 + r];
    }

    f32x4 acc[8];
#pragma unroll
    for (int nf = 0; nf < 8; ++nf) acc[nf] = (f32x4){0.f, 0.f, 0.f, 0.f};

    const short* bbase = WeT + (size_t)lr * D + lk * 8;
#pragma unroll
    for (int nf = 0; nf < 8; ++nf) {
#pragma unroll
        for (int ks = 0; ks < 4; ++ks) {
            bf16x8 bf = *(const bf16x8*)(bbase + nf * 16 * D + ks * 32);
            acc[nf] = __builtin_amdgcn_mfma_f32_16x16x32_bf16(af[ks], bf, acc[nf], 0, 0, 0);
        }
    }

    // epilogue: per (dim-frag, edge-reg): gather q/k/v, gate, atomic scatter
#pragma unroll
    for (int nf = 0; nf < 8; ++nf) {
        int c = nf * 16 + lr;
        float wb = web[c];
#pragma unroll
        for (int r = 0; r < 4; ++r) {
            float q  = Qp[(size_t)ridx[r] * D + c];
            float kk = Kp[(size_t)sidx[r] * D + c];
            float v  = Vp[(size_t)sidx[r] * D + c];
            float x  = acc[nf][r] + q + kk + wb;
            float g  = 1.f / (1.f + __expf(-x));
            atomicAdd(out + (size_t)ridx[r] * D + c, g * v);
        }
    }
}

extern "C" void kernel_launch(void* const* d_in, const int* in_sizes, int n_in,
                              void* d_out, int out_size, void* d_ws, size_t ws_size,
                              hipStream_t stream)
{
    const float* X   = (const float*)d_in[0];
    const int*   snd = (const int*)  d_in[1];
    const int*   rcv = (const int*)  d_in[2];
    const float* EF  = (const float*)d_in[3];
    const float* W   = (const float*)d_in[4];
    const float* Wb  = (const float*)d_in[5];
    const float* We  = (const float*)d_in[6];
    const float* Web = (const float*)d_in[7];
    float* out = (float*)d_out;

    float* Qp = (float*)d_ws;                        // [NN][128] f32
    float* Kp = Qp + (size_t)NN * D;
    float* Vp = Kp + (size_t)NN * D;
    short* WT  = (short*)(Vp + (size_t)NN * D);      // [512][128] bf16
    short* WeT = WT + 512 * 128;                     // [128][128] bf16

    transpose_cast_kernel<<<256, 256, 0, stream>>>(W, We, WT, WeT);

    node_proj_kernel<<<NN / 16, 256, 0, stream>>>(X, WT, Wb, out, Qp, Kp, Vp);

    edge_kernel<<<NE / 64, 256, 0, stream>>>(EF, snd, rcv, WeT, Web, Qp, Kp, Vp, out);
}